// Round 11
// baseline (278.349 us; speedup 1.0000x reference)
//
#include <hip/hip_runtime.h>

#define NUM_DEM 2
#define VOCAB 10000
#define EMB 128
#define NROWS 16384
#define ROWLEN (NUM_DEM + VOCAB)      // 10002
#define NITER 79                      // BK=128 iterations (ceil(10000/128))
#define TILES (NITER * 4)             // 316 step-tiles (steps 313..315 are zero pad)
#define PCOLS 132                     // partial row stride: 128 pooled + 1 count + pad
#define BPACK_USHORTS ((size_t)TILES * 4096)
#define BPACK_BYTES (BPACK_USHORTS * 2)
#define NCH 4

typedef float f32x4 __attribute__((ext_vector_type(4)));
typedef __bf16 bf16x8 __attribute__((ext_vector_type(8)));
typedef short s16x8 __attribute__((ext_vector_type(8)));

union Frag {
    s16x8 s;
    bf16x8 b;
    unsigned int u[4];
};

__device__ __forceinline__ unsigned short f2bf_rtne(float f) {
    unsigned int u = __float_as_uint(f);
    u += 0x7FFFu + ((u >> 16) & 1u);
    return (unsigned short)(u >> 16);
}

// ---------------- kernel 0: pack embed (fp32 -> bf16 B fragments, BK=128 order) -----
// Step tile t = iter*4 + s. Fragment elem (lane l, j):
//   k = iter*128 + 32*(l>>4) + 8*s + j   (matches A's contiguous-load slot mapping)
//   bp[((t*8 + c)*64 + l)*8 + j] = bf16(embed[k][c*16 + (l&15)]), 0 if k >= VOCAB
__global__ void pack_embed_k(const float* __restrict__ embed,
                             unsigned short* __restrict__ bp) {
    int id = blockIdx.x * blockDim.x + threadIdx.x;
    if (id >= TILES * 8 * 64) return;
    int l = id & 63;
    int c = (id >> 6) & 7;
    int t = id >> 9;
    int iter = t >> 2, s = t & 3;
    int kbase = iter * 128 + 32 * (l >> 4) + 8 * s;
    int n = c * 16 + (l & 15);
    unsigned short v[8];
#pragma unroll
    for (int j = 0; j < 8; ++j) {
        int k = kbase + j;
        float f = (k < VOCAB) ? embed[(size_t)k * EMB + n] : 0.0f;
        v[j] = f2bf_rtne(f);
    }
    uint4 w;
    w.x = (unsigned int)v[0] | ((unsigned int)v[1] << 16);
    w.y = (unsigned int)v[2] | ((unsigned int)v[3] << 16);
    w.z = (unsigned int)v[4] | ((unsigned int)v[5] << 16);
    w.w = (unsigned int)v[6] | ((unsigned int)v[7] << 16);
    *reinterpret_cast<uint4*>(bp + (size_t)id * 8) = w;
}

// ---------------- kernel 1: split-K masked-sum GEMM, BK=128, contiguous A -----------
// R6's proven 2-barrier structure, but each iter covers 128 k: every lane loads
// 128 CONTIGUOUS bytes of A (32 fp32), so each row's DRAM visit is 512 B instead
// of 128 B -> 4x fewer row activates per byte (DRAM page-locality fix).
typedef const __attribute__((address_space(1))) unsigned int* gas_u32p;
typedef __attribute__((address_space(3))) unsigned int* las_u32p;
#define GLOAD_LDS16(g, l)                                                              \
    __builtin_amdgcn_global_load_lds((gas_u32p)(g), (las_u32p)(l), 16, 0, 0)

#define PERM_A(dst, x0, x1)                                                            \
    dst.u[0] = __builtin_amdgcn_perm(__float_as_uint(x0.y), __float_as_uint(x0.x),     \
                                     0x07060302u);                                     \
    dst.u[1] = __builtin_amdgcn_perm(__float_as_uint(x0.w), __float_as_uint(x0.z),     \
                                     0x07060302u);                                     \
    dst.u[2] = __builtin_amdgcn_perm(__float_as_uint(x1.y), __float_as_uint(x1.x),     \
                                     0x07060302u);                                     \
    dst.u[3] = __builtin_amdgcn_perm(__float_as_uint(x1.w), __float_as_uint(x1.z),     \
                                     0x07060302u);

__global__ __launch_bounds__(256, 4) void main_gemm_k(
    const float* __restrict__ src, const unsigned short* __restrict__ bp,
    float* __restrict__ part, int nch) {
    __shared__ alignas(16) unsigned short ldsB[4 * 4096];  // 32 KB: one BK=128 B tile

    const int tid = threadIdx.x;
    const int lane = tid & 63;
    const int wid = tid >> 6;
    const int rb = blockIdx.x & 255;  // row block: 64 rows
    const int ch = blockIdx.x >> 8;   // K chunk (iter-granular)
    const int I0 = (NITER * ch) / nch;
    const int I1 = (NITER * (ch + 1)) / nch;

    const int rowbase = rb * 64 + wid * 16;
    const int arow = rowbase + (lane & 15);
    const int g = lane >> 4;
    const int k32 = 32 * g;  // lane's base within the iter's 128-k window
    const float* abase = src + (size_t)arow * ROWLEN + NUM_DEM + k32;

    f32x4 pacc[8];
#pragma unroll
    for (int f = 0; f < 8; ++f) pacc[f] = (f32x4){0.f, 0.f, 0.f, 0.f};
    f32x4 cacc = (f32x4){0.f, 0.f, 0.f, 0.f};

    Frag onesf;  // B fragment with col 0 == 1.0 (row counts), others 0
    {
        unsigned short o = ((lane & 15) == 0) ? (unsigned short)0x3F80 : (unsigned short)0;
        unsigned int ow = (unsigned int)o | ((unsigned int)o << 16);
        onesf.u[0] = ow; onesf.u[1] = ow; onesf.u[2] = ow; onesf.u[3] = ow;
    }

    for (int it = I0; it < I1; ++it) {
        // stage B tile (32 KB = 4 step-tiles) into LDS: 8 x 16B per thread, linear
        {
            const unsigned short* gB = bp + (size_t)it * 16384 + tid * 8;
            unsigned short* lB = ldsB + tid * 8;
#pragma unroll
            for (int q = 0; q < 8; ++q) GLOAD_LDS16(gB + q * 2048, lB + q * 2048);
        }

        // A: 32 contiguous fp32 per lane (128 B), conditional per 8-float group
        const int kb = it * 128;
        f32x4 z = (f32x4){0.f, 0.f, 0.f, 0.f};
        f32x4 x0 = z, x1 = z, x2 = z, x3 = z, x4 = z, x5 = z, x6 = z, x7 = z;
        {
            const float* ap = abase + kb;
            if (kb + k32 + 8 <= VOCAB)  { x0 = *(const f32x4*)(ap);      x1 = *(const f32x4*)(ap + 4); }
            if (kb + k32 + 16 <= VOCAB) { x2 = *(const f32x4*)(ap + 8);  x3 = *(const f32x4*)(ap + 12); }
            if (kb + k32 + 24 <= VOCAB) { x4 = *(const f32x4*)(ap + 16); x5 = *(const f32x4*)(ap + 20); }
            if (kb + k32 + 32 <= VOCAB) { x6 = *(const f32x4*)(ap + 24); x7 = *(const f32x4*)(ap + 28); }
        }

        // perm to 4 A fragments (slot s: floats 8s..8s+7); exact for 0.0/1.0
        Frag af0, af1, af2, af3;
        PERM_A(af0, x0, x1);
        PERM_A(af1, x2, x3);
        PERM_A(af2, x4, x5);
        PERM_A(af3, x6, x7);

        __syncthreads();  // B tile resident

#pragma unroll
        for (int s = 0; s < 4; ++s) {
            const Frag& af = (s == 0) ? af0 : (s == 1) ? af1 : (s == 2) ? af2 : af3;
            const unsigned short* rB = ldsB + s * 4096 + lane * 8;
#pragma unroll
            for (int f = 0; f < 8; ++f) {
                Frag bfr;
                bfr.s = *reinterpret_cast<const s16x8*>(rB + f * 512);
                pacc[f] = __builtin_amdgcn_mfma_f32_16x16x32_bf16(af.b, bfr.b, pacc[f], 0, 0, 0);
            }
            cacc = __builtin_amdgcn_mfma_f32_16x16x32_bf16(af.b, onesf.b, cacc, 0, 0, 0);
        }

        __syncthreads();  // protect LDS before next stage
    }

    // epilogue: C/D layout col = lane&15, row = (lane>>4)*4 + reg
    const int rlo = (lane >> 4) * 4;
    float* pch = part + (size_t)ch * NROWS * PCOLS;
#pragma unroll
    for (int f = 0; f < 8; ++f) {
#pragma unroll
        for (int r = 0; r < 4; ++r) {
            int row = rowbase + rlo + r;
            pch[(size_t)row * PCOLS + f * 16 + (lane & 15)] = pacc[f][r];
        }
    }
    if ((lane & 15) == 0) {
#pragma unroll
        for (int r = 0; r < 4; ++r) {
            int row = rowbase + rlo + r;
            pch[(size_t)row * PCOLS + 128] = cacc[r];
        }
    }
}

// ---------------- kernel 2: reduce partials + MLP ----------------------------------
__global__ __launch_bounds__(256) void mlp_k(const float* __restrict__ part,
                                             const float* __restrict__ src,
                                             const float* __restrict__ W1,
                                             const float* __restrict__ b1,
                                             const float* __restrict__ W2,
                                             const float* __restrict__ b2,
                                             float* __restrict__ out, int nch) {
    __shared__ float xls[16][131];  // [dem(2), pooled(128)] per row
    __shared__ float hls[16][16];
    __shared__ float cnt[16];
    const int tid = threadIdx.x;
    const int rb = blockIdx.x * 16;

    if (tid < 16) {
        float s = 0.f;
        for (int c = 0; c < nch; ++c)
            s += part[((size_t)c * NROWS + rb + tid) * PCOLS + 128];
        cnt[tid] = s;
    }
    if (tid >= 16 && tid < 48) {
        int r = (tid - 16) >> 1, d = (tid - 16) & 1;
        xls[r][d] = src[(size_t)(rb + r) * ROWLEN + d];
    }
    __syncthreads();

    for (int idx = tid; idx < 16 * 128; idx += 256) {
        int r = idx >> 7, col = idx & 127;
        float s = 0.f;
        for (int c = 0; c < nch; ++c)
            s += part[((size_t)c * NROWS + rb + r) * PCOLS + col];
        xls[r][NUM_DEM + col] = s / cnt[r];
    }
    __syncthreads();

    {
        int r = tid >> 4, u = tid & 15;
        float acc = b1[u];
        for (int i = 0; i < NUM_DEM + EMB; ++i) acc += xls[r][i] * W1[i * 16 + u];
        hls[r][u] = tanhf(acc);
    }
    __syncthreads();

    if (tid < 32) {
        int r = tid >> 1, o = tid & 1;
        float acc = b2[o];
#pragma unroll
        for (int u = 0; u < 16; ++u) acc += hls[r][u] * W2[u * 2 + o];
        out[(size_t)(rb + r) * 2 + o] = acc;
    }
}

// ---------------- launch ------------------------------------------------------------
extern "C" void kernel_launch(void* const* d_in, const int* in_sizes, int n_in,
                              void* d_out, int out_size, void* d_ws, size_t ws_size,
                              hipStream_t stream) {
    const float* src = (const float*)d_in[0];
    const float* embed = (const float*)d_in[1];
    const float* W1 = (const float*)d_in[2];
    const float* b1 = (const float*)d_in[3];
    const float* W2 = (const float*)d_in[4];
    const float* b2 = (const float*)d_in[5];
    float* out = (float*)d_out;

    unsigned short* bpack = (unsigned short*)d_ws;
    float* part = (float*)((char*)d_ws + BPACK_BYTES);

    const size_t part1 = (size_t)NROWS * PCOLS * sizeof(float);
    int nch = NCH;
    while (nch > 1 && BPACK_BYTES + part1 * (size_t)nch > ws_size) nch >>= 1;

    hipLaunchKernelGGL(pack_embed_k, dim3((TILES * 8 * 64 + 255) / 256), dim3(256), 0,
                       stream, embed, bpack);
    hipLaunchKernelGGL(main_gemm_k, dim3(256 * nch), dim3(256), 0, stream, src, bpack,
                       part, nch);
    hipLaunchKernelGGL(mlp_k, dim3(NROWS / 16), dim3(256), 0, stream, part, src, W1, b1,
                       W2, b2, out, nch);
}

// Round 12
// 209.800 us; speedup vs baseline: 1.3267x; 1.3267x over previous
//
#include <hip/hip_runtime.h>

#define NUM_DEM 2
#define VOCAB 10000
#define EMB 128
#define NROWS 16384
#define ROWLEN (NUM_DEM + VOCAB)      // 10002
#define KSTEPS 313                    // ceil(10000/32)
#define TILES (KSTEPS + 1)            // +1 zero pad tile (pipeline may stage step 313)
#define NITER 157                     // BK=64 iterations total
#define PCOLS 132                     // partial row stride: 128 pooled + 1 count + pad
#define BPACK_USHORTS ((size_t)TILES * 4096)
#define BPACK_BYTES (BPACK_USHORTS * 2)
#define NCH 4

typedef float f32x4 __attribute__((ext_vector_type(4)));
typedef __bf16 bf16x8 __attribute__((ext_vector_type(8)));
typedef short s16x8 __attribute__((ext_vector_type(8)));

union Frag {
    s16x8 s;
    bf16x8 b;
    unsigned int u[4];
};

__device__ __forceinline__ unsigned short f2bf_rtne(float f) {
    unsigned int u = __float_as_uint(f);
    u += 0x7FFFu + ((u >> 16) & 1u);
    return (unsigned short)(u >> 16);
}

// ---------------- kernel 0: pack embed (fp32 -> bf16 MFMA-B fragment order) ---------
// Bpack[((t*8 + c)*64 + l)*8 + j] = bf16(embed[t*32 + (l>>4)*8 + j][c*16 + (l&15)])
// t == 313 is an all-zero pad tile (kbase >= VOCAB).
__global__ void pack_embed_k(const float* __restrict__ embed,
                             unsigned short* __restrict__ bp) {
    int id = blockIdx.x * blockDim.x + threadIdx.x;
    if (id >= TILES * 8 * 64) return;
    int l = id & 63;
    int c = (id >> 6) & 7;
    int t = id >> 9;
    int kbase = t * 32 + ((l >> 4) * 8);
    int n = c * 16 + (l & 15);
    unsigned short v[8];
#pragma unroll
    for (int j = 0; j < 8; ++j) {
        int k = kbase + j;
        float f = (k < VOCAB) ? embed[(size_t)k * EMB + n] : 0.0f;
        v[j] = f2bf_rtne(f);
    }
    uint4 w;
    w.x = (unsigned int)v[0] | ((unsigned int)v[1] << 16);
    w.y = (unsigned int)v[2] | ((unsigned int)v[3] << 16);
    w.z = (unsigned int)v[4] | ((unsigned int)v[5] << 16);
    w.w = (unsigned int)v[6] | ((unsigned int)v[7] << 16);
    *reinterpret_cast<uint4*>(bp + (size_t)id * 8) = w;
}

// ---------------- kernel 1: split-K masked-sum GEMM, counted-vmcnt pipeline ---------
// R10 structure EXACTLY, with one change: K-chunk is derived from blockIdx&7 so
// (under round-robin block->XCD dispatch) each XCD pair reads ONE 640 KB bpack
// chunk -> B staging becomes L2-resident instead of ~655 MB of HBM re-reads.
typedef const __attribute__((address_space(1))) unsigned int* gas_u32p;
typedef __attribute__((address_space(3))) unsigned int* las_u32p;
#define GLOAD_LDS16(g, l)                                                              \
    __builtin_amdgcn_global_load_lds((gas_u32p)(g), (las_u32p)(l), 16, 0, 0)

#define PERM_A(dst, x0, x1)                                                            \
    dst.u[0] = __builtin_amdgcn_perm(__float_as_uint(x0.y), __float_as_uint(x0.x),     \
                                     0x07060302u);                                     \
    dst.u[1] = __builtin_amdgcn_perm(__float_as_uint(x0.w), __float_as_uint(x0.z),     \
                                     0x07060302u);                                     \
    dst.u[2] = __builtin_amdgcn_perm(__float_as_uint(x1.y), __float_as_uint(x1.x),     \
                                     0x07060302u);                                     \
    dst.u[3] = __builtin_amdgcn_perm(__float_as_uint(x1.w), __float_as_uint(x1.z),     \
                                     0x07060302u);

#define WAITVM(N) asm volatile("s_waitcnt vmcnt(" #N ")" ::: "memory")

// stage iter G's two 32-k tiles (2*G, 2*G+1) into LDS buffer BUF: 4 x 16B per thread
#define STAGE_B(G, BUF)                                                                \
    {                                                                                  \
        const unsigned short* gB_ =                                                    \
            bp + (size_t)(2 * (G)) * 4096 + wid * 1024 + lane * 8;                     \
        unsigned short* lB_ = &ldsB[BUF][0] + wid * 1024 + lane * 8;                   \
        GLOAD_LDS16(gB_, lB_);                                                         \
        GLOAD_LDS16(gB_ + 512, lB_ + 512);                                             \
        GLOAD_LDS16(gB_ + 4096, lB_ + 4096);                                           \
        GLOAD_LDS16(gB_ + 4096 + 512, lB_ + 4096 + 512);                               \
    }

// unconditional clamped A loads for iter G (4 vmem): OOB groups zeroed at consume
#define LOAD_A2(G, A0, A1, A2, A3)                                                     \
    {                                                                                  \
        const int s0_ = 2 * (G), s1_ = s0_ + 1;                                        \
        const f32x4* p0_ = reinterpret_cast<const f32x4*>(                             \
            asrc + ((s0_ * 32 + kgrp8 + 8 <= VOCAB) ? (size_t)(s0_ * 32) : (size_t)0));\
        const f32x4* p1_ = reinterpret_cast<const f32x4*>(                             \
            asrc + ((s1_ * 32 + kgrp8 + 8 <= VOCAB) ? (size_t)(s1_ * 32) : (size_t)0));\
        A0 = p0_[0];                                                                   \
        A1 = p0_[1];                                                                   \
        A2 = p1_[0];                                                                   \
        A3 = p1_[1];                                                                   \
    }

#define BODY(G, BUF, A0, A1, A2, A3, DOPF, PFG, N)                                     \
    {                                                                                  \
        WAITVM(N);                                                                     \
        __builtin_amdgcn_s_barrier();                                                  \
        asm volatile("" ::: "memory"); /* pin ds_reads below the barrier */            \
        {                                                                              \
            const int s0_ = 2 * (G), s1_ = s0_ + 1;                                    \
            Frag af0_, af1_;                                                           \
            PERM_A(af0_, A0, A1); /* fp32 0/1 -> bf16 truncation exact */              \
            PERM_A(af1_, A2, A3);                                                      \
            unsigned v0_ = (s0_ * 32 + kgrp8 + 8 <= VOCAB) ? 0xFFFFFFFFu : 0u;         \
            unsigned v1_ = (s1_ * 32 + kgrp8 + 8 <= VOCAB) ? 0xFFFFFFFFu : 0u;         \
            af0_.u[0] &= v0_; af0_.u[1] &= v0_; af0_.u[2] &= v0_; af0_.u[3] &= v0_;    \
            af1_.u[0] &= v1_; af1_.u[1] &= v1_; af1_.u[2] &= v1_; af1_.u[3] &= v1_;    \
            const unsigned short* rB_ = &ldsB[BUF][0] + lane * 8;                      \
            _Pragma("unroll") for (int f = 0; f < 8; ++f) {                            \
                Frag bfr_;                                                             \
                bfr_.s = *reinterpret_cast<const s16x8*>(rB_ + f * 512);               \
                pacc[f] = __builtin_amdgcn_mfma_f32_16x16x32_bf16(af0_.b, bfr_.b,      \
                                                                  pacc[f], 0, 0, 0);   \
            }                                                                          \
            cacc = __builtin_amdgcn_mfma_f32_16x16x32_bf16(af0_.b, onesf.b, cacc, 0,   \
                                                           0, 0);                      \
            _Pragma("unroll") for (int f = 0; f < 8; ++f) {                            \
                Frag bfr_;                                                             \
                bfr_.s = *reinterpret_cast<const s16x8*>(rB_ + 4096 + f * 512);        \
                pacc[f] = __builtin_amdgcn_mfma_f32_16x16x32_bf16(af1_.b, bfr_.b,      \
                                                                  pacc[f], 0, 0, 0);   \
            }                                                                          \
            cacc = __builtin_amdgcn_mfma_f32_16x16x32_bf16(af1_.b, onesf.b, cacc, 0,   \
                                                           0, 0);                      \
        }                                                                              \
        asm volatile("" ::: "memory"); /* pin ds_reads above this barrier */           \
        __builtin_amdgcn_s_barrier();                                                  \
        __builtin_amdgcn_sched_barrier(0);                                             \
        if (DOPF) {                                                                    \
            STAGE_B(PFG, BUF);                                                         \
            LOAD_A2(PFG, A0, A1, A2, A3);                                              \
        }                                                                              \
    }

__global__ __launch_bounds__(256, 4) void main_gemm_k(
    const float* __restrict__ src, const unsigned short* __restrict__ bp,
    float* __restrict__ part, int nch) {
    __shared__ alignas(16) unsigned short ldsB[2][2 * 4096];  // 32 KB double buffer

    const int tid = threadIdx.x;
    const int lane = tid & 63;
    const int wid = tid >> 6;
    // XCD-pinned chunk mapping (bijective): xcd = blockIdx&7 (empirical round-robin),
    // ch = xcd>>1, rb = (blockIdx>>3)*2 + (blockIdx&1)  ->  each XCD pair reads ONE
    // 640 KB bpack chunk.
    const int bx = blockIdx.x;
    const int ch = (bx & 7) >> 1;
    const int rb = ((bx >> 3) << 1) | (bx & 1);
    const int I0 = (NITER * ch) / NCH;
    const int I1 = (NITER * (ch + 1)) / NCH;
    const int nIter = I1 - I0;  // 39 or 40

    const int rowbase = rb * 64 + wid * 16;
    const int arow = rowbase + (lane & 15);
    const int kgrp8 = (lane >> 4) * 8;
    const float* asrc = src + (size_t)arow * ROWLEN + NUM_DEM + kgrp8;

    f32x4 pacc[8];
#pragma unroll
    for (int f = 0; f < 8; ++f) pacc[f] = (f32x4){0.f, 0.f, 0.f, 0.f};
    f32x4 cacc = (f32x4){0.f, 0.f, 0.f, 0.f};

    Frag onesf;  // B fragment with col 0 == 1.0 (row counts), others 0
    {
        unsigned short o = ((lane & 15) == 0) ? (unsigned short)0x3F80 : (unsigned short)0;
        unsigned int ow = (unsigned int)o | ((unsigned int)o << 16);
        onesf.u[0] = ow; onesf.u[1] = ow; onesf.u[2] = ow; onesf.u[3] = ow;
    }

    f32x4 aP0, aP1, aP2, aP3, aQ0, aQ1, aQ2, aQ3;  // A slots, parity-named (rule #20)

    // prologue: iters I0 -> buf0/P, I0+1 -> buf1/Q (groups fenced for vmcnt order)
    STAGE_B(I0, 0);
    LOAD_A2(I0, aP0, aP1, aP2, aP3);
    asm volatile("" ::: "memory");
    STAGE_B(I0 + 1, 1);
    LOAD_A2(I0 + 1, aQ0, aQ1, aQ2, aQ3);
    // outstanding: B(0),A(0),B(1),A(1) = 16 vmem

    int i = 0;
    for (; i + 3 < nIter; i += 2) {
        BODY(I0 + i, 0, aP0, aP1, aP2, aP3, 1, I0 + i + 2, 8);
        BODY(I0 + i + 1, 1, aQ0, aQ1, aQ2, aQ3, 1, I0 + i + 3, 8);
    }
    if (nIter - i == 3) {
        BODY(I0 + i, 0, aP0, aP1, aP2, aP3, 1, I0 + i + 2, 8);
        BODY(I0 + i + 1, 1, aQ0, aQ1, aQ2, aQ3, 0, 0, 8);
        BODY(I0 + i + 2, 0, aP0, aP1, aP2, aP3, 0, 0, 0);
    } else {  // nIter - i == 2
        BODY(I0 + i, 0, aP0, aP1, aP2, aP3, 0, 0, 8);
        BODY(I0 + i + 1, 1, aQ0, aQ1, aQ2, aQ3, 0, 0, 0);
    }

    // epilogue: C/D layout col = lane&15, row = (lane>>4)*4 + reg
    const int rlo = (lane >> 4) * 4;
    float* pch = part + (size_t)ch * NROWS * PCOLS;
#pragma unroll
    for (int f = 0; f < 8; ++f) {
#pragma unroll
        for (int r = 0; r < 4; ++r) {
            int row = rowbase + rlo + r;
            pch[(size_t)row * PCOLS + f * 16 + (lane & 15)] = pacc[f][r];
        }
    }
    if ((lane & 15) == 0) {
#pragma unroll
        for (int r = 0; r < 4; ++r) {
            int row = rowbase + rlo + r;
            pch[(size_t)row * PCOLS + 128] = cacc[r];
        }
    }
}

// ---------------- kernel 2: reduce partials + MLP ----------------------------------
__global__ __launch_bounds__(256) void mlp_k(const float* __restrict__ part,
                                             const float* __restrict__ src,
                                             const float* __restrict__ W1,
                                             const float* __restrict__ b1,
                                             const float* __restrict__ W2,
                                             const float* __restrict__ b2,
                                             float* __restrict__ out, int nch) {
    __shared__ float xls[16][131];  // [dem(2), pooled(128)] per row
    __shared__ float hls[16][16];
    __shared__ float cnt[16];
    const int tid = threadIdx.x;
    const int rb = blockIdx.x * 16;

    if (tid < 16) {
        float s = 0.f;
        for (int c = 0; c < nch; ++c)
            s += part[((size_t)c * NROWS + rb + tid) * PCOLS + 128];
        cnt[tid] = s;
    }
    if (tid >= 16 && tid < 48) {
        int r = (tid - 16) >> 1, d = (tid - 16) & 1;
        xls[r][d] = src[(size_t)(rb + r) * ROWLEN + d];
    }
    __syncthreads();

    for (int idx = tid; idx < 16 * 128; idx += 256) {
        int r = idx >> 7, col = idx & 127;
        float s = 0.f;
        for (int c = 0; c < nch; ++c)
            s += part[((size_t)c * NROWS + rb + r) * PCOLS + col];
        xls[r][NUM_DEM + col] = s / cnt[r];
    }
    __syncthreads();

    {
        int r = tid >> 4, u = tid & 15;
        float acc = b1[u];
        for (int i = 0; i < NUM_DEM + EMB; ++i) acc += xls[r][i] * W1[i * 16 + u];
        hls[r][u] = tanhf(acc);
    }
    __syncthreads();

    if (tid < 32) {
        int r = tid >> 1, o = tid & 1;
        float acc = b2[o];
#pragma unroll
        for (int u = 0; u < 16; ++u) acc += hls[r][u] * W2[u * 2 + o];
        out[(size_t)(rb + r) * 2 + o] = acc;
    }
}

// ---------------- launch ------------------------------------------------------------
extern "C" void kernel_launch(void* const* d_in, const int* in_sizes, int n_in,
                              void* d_out, int out_size, void* d_ws, size_t ws_size,
                              hipStream_t stream) {
    const float* src = (const float*)d_in[0];
    const float* embed = (const float*)d_in[1];
    const float* W1 = (const float*)d_in[2];
    const float* b1 = (const float*)d_in[3];
    const float* W2 = (const float*)d_in[4];
    const float* b2 = (const float*)d_in[5];
    float* out = (float*)d_out;

    unsigned short* bpack = (unsigned short*)d_ws;
    float* part = (float*)((char*)d_ws + BPACK_BYTES);

    hipLaunchKernelGGL(pack_embed_k, dim3((TILES * 8 * 64 + 255) / 256), dim3(256), 0,
                       stream, embed, bpack);
    hipLaunchKernelGGL(main_gemm_k, dim3(256 * NCH), dim3(256), 0, stream, src, bpack,
                       part, NCH);
    hipLaunchKernelGGL(mlp_k, dim3(NROWS / 16), dim3(256), 0, stream, part, src, W1, b1,
                       W2, b2, out, NCH);
}

// Round 13
// 197.239 us; speedup vs baseline: 1.4112x; 1.0637x over previous
//
#include <hip/hip_runtime.h>

#define NUM_DEM 2
#define VOCAB 10000
#define EMB 128
#define NROWS 16384
#define ROWLEN (NUM_DEM + VOCAB)      // 10002
#define KSTEPS 313                    // ceil(10000/32)
#define PCOLS 132                     // partial row stride: 128 pooled + 1 count + pad
#define BPACK_USHORTS ((size_t)KSTEPS * 4096)
#define BPACK_BYTES (BPACK_USHORTS * 2)
#define NCH 4

typedef float f32x4 __attribute__((ext_vector_type(4)));
typedef __bf16 bf16x8 __attribute__((ext_vector_type(8)));
typedef short s16x8 __attribute__((ext_vector_type(8)));

union Frag {
    s16x8 s;
    bf16x8 b;
    unsigned int u[4];
};

__device__ __forceinline__ unsigned short f2bf_rtne(float f) {
    unsigned int u = __float_as_uint(f);
    u += 0x7FFFu + ((u >> 16) & 1u);
    return (unsigned short)(u >> 16);
}

// ---------------- kernel 0: pack embed (fp32 -> bf16 MFMA-B fragment order) ---------
// Bpack[((t*8 + c)*64 + l)*8 + j] = bf16(embed[t*32 + (l>>4)*8 + j][c*16 + (l&15)])
__global__ void pack_embed_k(const float* __restrict__ embed,
                             unsigned short* __restrict__ bp) {
    int id = blockIdx.x * blockDim.x + threadIdx.x;
    if (id >= KSTEPS * 8 * 64) return;
    int l = id & 63;
    int c = (id >> 6) & 7;
    int t = id >> 9;
    int kbase = t * 32 + ((l >> 4) * 8);
    int n = c * 16 + (l & 15);
    unsigned short v[8];
#pragma unroll
    for (int j = 0; j < 8; ++j) {
        int k = kbase + j;
        float f = (k < VOCAB) ? embed[(size_t)k * EMB + n] : 0.0f;
        v[j] = f2bf_rtne(f);
    }
    uint4 w;
    w.x = (unsigned int)v[0] | ((unsigned int)v[1] << 16);
    w.y = (unsigned int)v[2] | ((unsigned int)v[3] << 16);
    w.z = (unsigned int)v[4] | ((unsigned int)v[5] << 16);
    w.w = (unsigned int)v[6] | ((unsigned int)v[7] << 16);
    *reinterpret_cast<uint4*>(bp + (size_t)id * 8) = w;
}

// ---------------- kernel 1: split-K masked-sum GEMM via MFMA ------------------------
// R6's proven 2-barrier BK=64 structure, but M-tile = 128 rows (512 threads, 8
// waves): B-restaging traffic halves (655 -> 327 MB) since each block amortizes
// its 640 KB bpack chunk over 2x the rows. (512,4) -> 2 blocks/CU = 32 waves/CU.
typedef const __attribute__((address_space(1))) unsigned int* gas_u32p;
typedef __attribute__((address_space(3))) unsigned int* las_u32p;
#define GLOAD_LDS16(g, l)                                                              \
    __builtin_amdgcn_global_load_lds((gas_u32p)(g), (las_u32p)(l), 16, 0, 0)

#define PERM_A(dst, x0, x1)                                                            \
    dst.u[0] = __builtin_amdgcn_perm(__float_as_uint(x0.y), __float_as_uint(x0.x),     \
                                     0x07060302u);                                     \
    dst.u[1] = __builtin_amdgcn_perm(__float_as_uint(x0.w), __float_as_uint(x0.z),     \
                                     0x07060302u);                                     \
    dst.u[2] = __builtin_amdgcn_perm(__float_as_uint(x1.y), __float_as_uint(x1.x),     \
                                     0x07060302u);                                     \
    dst.u[3] = __builtin_amdgcn_perm(__float_as_uint(x1.w), __float_as_uint(x1.z),     \
                                     0x07060302u);

__global__ __launch_bounds__(512, 4) void main_gemm_k(
    const float* __restrict__ src, const unsigned short* __restrict__ bp,
    float* __restrict__ part, int nch) {
    __shared__ alignas(16) unsigned short ldsB[2 * 4096];  // 16 KB: two K-step B tiles

    const int tid = threadIdx.x;
    const int lane = tid & 63;
    const int wid = tid >> 6;        // 0..7
    const int rb = blockIdx.x & 127; // row block: 128 rows
    const int ch = blockIdx.x >> 7;  // K chunk
    const int t0 = (KSTEPS * ch) / nch;
    const int t1 = (KSTEPS * (ch + 1)) / nch;

    const int rowbase = rb * 128 + wid * 16;
    const int arow = rowbase + (lane & 15);
    const int kgrp8 = (lane >> 4) * 8;
    const float* asrc = src + (size_t)arow * ROWLEN + NUM_DEM + kgrp8;

    f32x4 pacc[8];
#pragma unroll
    for (int f = 0; f < 8; ++f) pacc[f] = (f32x4){0.f, 0.f, 0.f, 0.f};
    f32x4 cacc = (f32x4){0.f, 0.f, 0.f, 0.f};

    Frag onesf;  // B fragment with col 0 == 1.0 (for row counts), others 0
    {
        unsigned short o = ((lane & 15) == 0) ? (unsigned short)0x3F80 : (unsigned short)0;
        unsigned int ow = (unsigned int)o | ((unsigned int)o << 16);
        onesf.u[0] = ow; onesf.u[1] = ow; onesf.u[2] = ow; onesf.u[3] = ow;
    }

    int t = t0;
    for (; t + 2 <= t1; t += 2) {
        // stage B(t) -> buf0, B(t+1) -> buf1: 2 x 16B per thread (512 threads cover
        // each 8 KB tile exactly once)
        {
            const unsigned short* gB = bp + (size_t)t * 4096 + tid * 8;
            unsigned short* lB = ldsB + tid * 8;
            GLOAD_LDS16(gB, lB);
            GLOAD_LDS16(gB + 4096, lB + 4096);
        }

        // A(t), A(t+1): plain caching loads; perm to bf16 immediately (regs die early)
        Frag af0, af1;
        {
            f32x4 z = (f32x4){0.f, 0.f, 0.f, 0.f};
            f32x4 a00 = z, a01 = z, a10 = z, a11 = z;
            if (t * 32 + kgrp8 + 8 <= VOCAB) {
                const f32x4* ap = reinterpret_cast<const f32x4*>(asrc + (size_t)t * 32);
                a00 = ap[0];
                a01 = ap[1];
            }
            if ((t + 1) * 32 + kgrp8 + 8 <= VOCAB) {
                const f32x4* ap =
                    reinterpret_cast<const f32x4*>(asrc + (size_t)(t + 1) * 32);
                a10 = ap[0];
                a11 = ap[1];
            }
            PERM_A(af0, a00, a01);  // truncation fp32->bf16 exact for 0.0/1.0
            PERM_A(af1, a10, a11);
        }

        __syncthreads();  // both B tiles resident

#pragma unroll
        for (int f = 0; f < 8; ++f) {
            Frag bfr;
            bfr.s = *reinterpret_cast<const s16x8*>(ldsB + f * 512 + lane * 8);
            pacc[f] = __builtin_amdgcn_mfma_f32_16x16x32_bf16(af0.b, bfr.b, pacc[f], 0, 0, 0);
        }
        cacc = __builtin_amdgcn_mfma_f32_16x16x32_bf16(af0.b, onesf.b, cacc, 0, 0, 0);
#pragma unroll
        for (int f = 0; f < 8; ++f) {
            Frag bfr;
            bfr.s = *reinterpret_cast<const s16x8*>(ldsB + 4096 + f * 512 + lane * 8);
            pacc[f] = __builtin_amdgcn_mfma_f32_16x16x32_bf16(af1.b, bfr.b, pacc[f], 0, 0, 0);
        }
        cacc = __builtin_amdgcn_mfma_f32_16x16x32_bf16(af1.b, onesf.b, cacc, 0, 0, 0);

        __syncthreads();  // protect LDS before next stage
    }
    if (t < t1) {  // odd tail (last chunk has 79 steps)
        {
            const unsigned short* gB = bp + (size_t)t * 4096 + tid * 8;
            GLOAD_LDS16(gB, ldsB + tid * 8);
        }
        Frag af0;
        {
            f32x4 z = (f32x4){0.f, 0.f, 0.f, 0.f};
            f32x4 a00 = z, a01 = z;
            if (t * 32 + kgrp8 + 8 <= VOCAB) {
                const f32x4* ap = reinterpret_cast<const f32x4*>(asrc + (size_t)t * 32);
                a00 = ap[0];
                a01 = ap[1];
            }
            PERM_A(af0, a00, a01);
        }
        __syncthreads();
#pragma unroll
        for (int f = 0; f < 8; ++f) {
            Frag bfr;
            bfr.s = *reinterpret_cast<const s16x8*>(ldsB + f * 512 + lane * 8);
            pacc[f] = __builtin_amdgcn_mfma_f32_16x16x32_bf16(af0.b, bfr.b, pacc[f], 0, 0, 0);
        }
        cacc = __builtin_amdgcn_mfma_f32_16x16x32_bf16(af0.b, onesf.b, cacc, 0, 0, 0);
        __syncthreads();
    }

    // epilogue: C/D layout col = lane&15, row = (lane>>4)*4 + reg
    const int rlo = (lane >> 4) * 4;
    float* pch = part + (size_t)ch * NROWS * PCOLS;
#pragma unroll
    for (int f = 0; f < 8; ++f) {
#pragma unroll
        for (int r = 0; r < 4; ++r) {
            int row = rowbase + rlo + r;
            pch[(size_t)row * PCOLS + f * 16 + (lane & 15)] = pacc[f][r];
        }
    }
    if ((lane & 15) == 0) {
#pragma unroll
        for (int r = 0; r < 4; ++r) {
            int row = rowbase + rlo + r;
            pch[(size_t)row * PCOLS + 128] = cacc[r];
        }
    }
}

// ---------------- kernel 2: reduce partials + MLP ----------------------------------
__global__ __launch_bounds__(256) void mlp_k(const float* __restrict__ part,
                                             const float* __restrict__ src,
                                             const float* __restrict__ W1,
                                             const float* __restrict__ b1,
                                             const float* __restrict__ W2,
                                             const float* __restrict__ b2,
                                             float* __restrict__ out, int nch) {
    __shared__ float xls[16][131];  // [dem(2), pooled(128)] per row
    __shared__ float hls[16][16];
    __shared__ float cnt[16];
    const int tid = threadIdx.x;
    const int rb = blockIdx.x * 16;

    if (tid < 16) {
        float s = 0.f;
        for (int c = 0; c < nch; ++c)
            s += part[((size_t)c * NROWS + rb + tid) * PCOLS + 128];
        cnt[tid] = s;
    }
    if (tid >= 16 && tid < 48) {
        int r = (tid - 16) >> 1, d = (tid - 16) & 1;
        xls[r][d] = src[(size_t)(rb + r) * ROWLEN + d];
    }
    __syncthreads();

    for (int idx = tid; idx < 16 * 128; idx += 256) {
        int r = idx >> 7, col = idx & 127;
        float s = 0.f;
        for (int c = 0; c < nch; ++c)
            s += part[((size_t)c * NROWS + rb + r) * PCOLS + col];
        xls[r][NUM_DEM + col] = s / cnt[r];
    }
    __syncthreads();

    {
        int r = tid >> 4, u = tid & 15;
        float acc = b1[u];
        for (int i = 0; i < NUM_DEM + EMB; ++i) acc += xls[r][i] * W1[i * 16 + u];
        hls[r][u] = tanhf(acc);
    }
    __syncthreads();

    if (tid < 32) {
        int r = tid >> 1, o = tid & 1;
        float acc = b2[o];
#pragma unroll
        for (int u = 0; u < 16; ++u) acc += hls[r][u] * W2[u * 2 + o];
        out[(size_t)(rb + r) * 2 + o] = acc;
    }
}

// ---------------- launch ------------------------------------------------------------
extern "C" void kernel_launch(void* const* d_in, const int* in_sizes, int n_in,
                              void* d_out, int out_size, void* d_ws, size_t ws_size,
                              hipStream_t stream) {
    const float* src = (const float*)d_in[0];
    const float* embed = (const float*)d_in[1];
    const float* W1 = (const float*)d_in[2];
    const float* b1 = (const float*)d_in[3];
    const float* W2 = (const float*)d_in[4];
    const float* b2 = (const float*)d_in[5];
    float* out = (float*)d_out;

    unsigned short* bpack = (unsigned short*)d_ws;
    float* part = (float*)((char*)d_ws + BPACK_BYTES);

    const size_t part1 = (size_t)NROWS * PCOLS * sizeof(float);
    int nch = NCH;
    while (nch > 1 && BPACK_BYTES + part1 * (size_t)nch > ws_size) nch >>= 1;

    hipLaunchKernelGGL(pack_embed_k, dim3((KSTEPS * 8 * 64 + 255) / 256), dim3(256), 0,
                       stream, embed, bpack);
    hipLaunchKernelGGL(main_gemm_k, dim3(128 * nch), dim3(512), 0, stream, src, bpack,
                       part, nch);
    hipLaunchKernelGGL(mlp_k, dim3(NROWS / 16), dim3(256), 0, stream, part, src, W1, b1,
                       W2, b2, out, nch);
}